// Round 1
// baseline (2914.172 us; speedup 1.0000x reference)
//
#include <hip/hip_runtime.h>

#define N_NODES 100000
#define N_EDGES 1600000
#define F 128
#define BN_EPS 1e-5f

// ---------------------------------------------------------------------------
// K1: h = node_feats @ W^T + b    (fp32, vector ALU)
// Writes h to BOTH ws_h (pristine gather source) and agg (=d_out, self-loop).
// Tile: 64 rows x 128 cols per block, K chunked by 32.
// ---------------------------------------------------------------------------
__global__ __launch_bounds__(256) void gemm_kernel(
    const float* __restrict__ A,     // [N_NODES,128]
    const float* __restrict__ W,     // [128,128] row-major [out][in]
    const float* __restrict__ bias,  // [128]
    float* __restrict__ h,           // [N_NODES,128]
    float* __restrict__ agg)         // [N_NODES,128]
{
    __shared__ float As[64 * 36];    // [r][k] stride 36 (16B-aligned rows, pad kills conflicts)
    __shared__ float Ws[32 * 132];   // [k][c] stride 132

    const int t   = threadIdx.x;
    const int tc  = t & 31;          // col group: cols c0..c0+3
    const int tr  = t >> 5;          // row group: rows r0..r0+7
    const int c0  = tc * 4;
    const int r0  = tr * 8;
    const int row0 = blockIdx.x * 64;

    float acc[8][4];
#pragma unroll
    for (int r = 0; r < 8; r++)
#pragma unroll
        for (int c = 0; c < 4; c++) acc[r][c] = 0.0f;

    for (int kc = 0; kc < 128; kc += 32) {
        __syncthreads();
        // A tile: 64 rows x 32 k = 512 float4, 2 per thread
#pragma unroll
        for (int i = 0; i < 2; i++) {
            int idx = t * 2 + i;         // 0..511
            int r   = idx >> 3;
            int k4  = idx & 7;
            int grow = row0 + r;
            float4 v = make_float4(0.f, 0.f, 0.f, 0.f);
            if (grow < N_NODES)
                v = *(const float4*)&A[(size_t)grow * F + kc + k4 * 4];
            *(float4*)&As[r * 36 + k4 * 4] = v;
        }
        // W tile transposed: for c in [0,128), k4 in [0,8): Ws[k][c] = W[c][kc+k]
#pragma unroll
        for (int i = 0; i < 4; i++) {
            int idx = t + i * 256;       // 0..1023
            int k4  = idx & 7;
            int c   = idx >> 3;
            float4 v = *(const float4*)&W[(size_t)c * F + kc + k4 * 4];
            Ws[(k4 * 4 + 0) * 132 + c] = v.x;
            Ws[(k4 * 4 + 1) * 132 + c] = v.y;
            Ws[(k4 * 4 + 2) * 132 + c] = v.z;
            Ws[(k4 * 4 + 3) * 132 + c] = v.w;
        }
        __syncthreads();

#pragma unroll
        for (int k4 = 0; k4 < 8; k4++) {
            float4 a4[8];
#pragma unroll
            for (int r = 0; r < 8; r++)
                a4[r] = *(const float4*)&As[(r0 + r) * 36 + k4 * 4];
            float4 w4[4];
#pragma unroll
            for (int j = 0; j < 4; j++)
                w4[j] = *(const float4*)&Ws[(k4 * 4 + j) * 132 + c0];
#pragma unroll
            for (int r = 0; r < 8; r++) {
                float4 a = a4[r];
                acc[r][0] += a.x * w4[0].x + a.y * w4[1].x + a.z * w4[2].x + a.w * w4[3].x;
                acc[r][1] += a.x * w4[0].y + a.y * w4[1].y + a.z * w4[2].y + a.w * w4[3].y;
                acc[r][2] += a.x * w4[0].z + a.y * w4[1].z + a.z * w4[2].z + a.w * w4[3].z;
                acc[r][3] += a.x * w4[0].w + a.y * w4[1].w + a.z * w4[2].w + a.w * w4[3].w;
            }
        }
    }

    float4 bv = *(const float4*)&bias[c0];
#pragma unroll
    for (int r = 0; r < 8; r++) {
        int grow = row0 + r0 + r;
        if (grow < N_NODES) {
            float4 o;
            o.x = acc[r][0] + bv.x;
            o.y = acc[r][1] + bv.y;
            o.z = acc[r][2] + bv.z;
            o.w = acc[r][3] + bv.w;
            *(float4*)&h[(size_t)grow * F + c0]   = o;
            *(float4*)&agg[(size_t)grow * F + c0] = o;
        }
    }
}

// ---------------------------------------------------------------------------
// K2: agg[dst] += h[src] over all edges. 32 threads per edge (float4 each).
// ---------------------------------------------------------------------------
__global__ __launch_bounds__(256) void scatter_kernel(
    const float* __restrict__ h,
    const int* __restrict__ src,
    const int* __restrict__ dst,
    float* __restrict__ agg)
{
    long long tid = (long long)blockIdx.x * blockDim.x + threadIdx.x;
    int e  = (int)(tid >> 5);
    int ch = (int)(tid & 31);
    if (e >= N_EDGES) return;
    int s = src[e];
    int d = dst[e];
    float4 v = *(const float4*)&h[(size_t)s * F + ch * 4];
    float* p = &agg[(size_t)d * F + ch * 4];
    unsafeAtomicAdd(p + 0, v.x);
    unsafeAtomicAdd(p + 1, v.y);
    unsafeAtomicAdd(p + 2, v.z);
    unsafeAtomicAdd(p + 3, v.w);
}

// ---------------------------------------------------------------------------
// K3: per-feature sum and sumsq over nodes. stats[0:128]=sum, [128:256]=sumsq
// ---------------------------------------------------------------------------
__global__ __launch_bounds__(256) void stats_kernel(
    const float* __restrict__ agg,
    float* __restrict__ stats)
{
    const int t    = threadIdx.x;
    const int tc   = t & 31;
    const int trow = t >> 5;     // 0..7
    const int c0   = tc * 4;

    float4 sum = make_float4(0.f, 0.f, 0.f, 0.f);
    float4 ss  = make_float4(0.f, 0.f, 0.f, 0.f);
    for (int r = blockIdx.x * 8 + trow; r < N_NODES; r += gridDim.x * 8) {
        float4 v = *(const float4*)&agg[(size_t)r * F + c0];
        sum.x += v.x; sum.y += v.y; sum.z += v.z; sum.w += v.w;
        ss.x  += v.x * v.x; ss.y += v.y * v.y; ss.z += v.z * v.z; ss.w += v.w * v.w;
    }

    __shared__ float red[256 * 8];
    float* my = &red[t * 8];
    my[0] = sum.x; my[1] = sum.y; my[2] = sum.z; my[3] = sum.w;
    my[4] = ss.x;  my[5] = ss.y;  my[6] = ss.z;  my[7] = ss.w;
    __syncthreads();

    if (t < 32) {
        float a8[8];
#pragma unroll
        for (int j = 0; j < 8; j++) a8[j] = red[t * 8 + j];
        for (int g = 1; g < 8; g++)
#pragma unroll
            for (int j = 0; j < 8; j++) a8[j] += red[(g * 32 + t) * 8 + j];
#pragma unroll
        for (int j = 0; j < 4; j++) {
            unsafeAtomicAdd(&stats[c0 + j],       a8[j]);
            unsafeAtomicAdd(&stats[128 + c0 + j], a8[4 + j]);
        }
    }
}

// ---------------------------------------------------------------------------
// K4: out = relu(gamma*(agg-mean)*rsqrt(var+eps)+beta) + node_feats (in-place)
// ---------------------------------------------------------------------------
__global__ __launch_bounds__(256) void finalize_kernel(
    const float* __restrict__ stats,
    const float* __restrict__ gamma,
    const float* __restrict__ beta,
    const float* __restrict__ x,
    float* __restrict__ agg)
{
    __shared__ float s_scale[128];
    __shared__ float s_shift[128];
    const int t = threadIdx.x;
    if (t < 128) {
        const float inv_n = 1.0f / (float)N_NODES;
        float mean = stats[t] * inv_n;
        float var  = stats[128 + t] * inv_n - mean * mean;
        float sc   = gamma[t] * rsqrtf(var + BN_EPS);
        s_scale[t] = sc;
        s_shift[t] = beta[t] - mean * sc;
    }
    __syncthreads();

    const long long total = (long long)N_NODES * F / 4;   // float4 count
    long long i0 = (long long)blockIdx.x * blockDim.x + t;

    // per-thread column block is fixed by i%32 only when stride keeps i%32
    // constant; grid stride is a multiple of 32 floats4? 256*gridDim may not
    // keep (i & 31) fixed, so recompute each iter (cheap).
    for (long long i = i0; i < total; i += (long long)gridDim.x * blockDim.x) {
        int cb = (int)(i & 31) * 4;
        float4 v  = ((const float4*)agg)[i];
        float4 xf = ((const float4*)x)[i];
        float4 o;
        o.x = fmaxf(v.x * s_scale[cb + 0] + s_shift[cb + 0], 0.f) + xf.x;
        o.y = fmaxf(v.y * s_scale[cb + 1] + s_shift[cb + 1], 0.f) + xf.y;
        o.z = fmaxf(v.z * s_scale[cb + 2] + s_shift[cb + 2], 0.f) + xf.z;
        o.w = fmaxf(v.w * s_scale[cb + 3] + s_shift[cb + 3], 0.f) + xf.w;
        ((float4*)agg)[i] = o;
    }
}

// ---------------------------------------------------------------------------
extern "C" void kernel_launch(void* const* d_in, const int* in_sizes, int n_in,
                              void* d_out, int out_size, void* d_ws, size_t ws_size,
                              hipStream_t stream) {
    const float* node_feats = (const float*)d_in[0];
    const float* W          = (const float*)d_in[1];
    const float* b          = (const float*)d_in[2];
    const float* gamma      = (const float*)d_in[3];
    const float* beta       = (const float*)d_in[4];
    const int*   src        = (const int*)d_in[5];
    const int*   dst        = (const int*)d_in[6];

    float* out   = (float*)d_out;
    float* stats = (float*)d_ws;                       // 256 floats
    float* h     = (float*)((char*)d_ws + 1024);       // N_NODES*128 floats

    // zero the stats accumulators (graph-capture-safe)
    hipMemsetAsync(d_ws, 0, 1024, stream);

    // K1: projection; writes h (scratch) and agg=out (self-loop init)
    gemm_kernel<<<(N_NODES + 63) / 64, 256, 0, stream>>>(node_feats, W, b, h, out);

    // K2: edge scatter-add
    const long long scatter_threads = (long long)N_EDGES * 32;
    scatter_kernel<<<(int)(scatter_threads / 256), 256, 0, stream>>>(h, src, dst, out);

    // K3: BN statistics
    stats_kernel<<<1024, 256, 0, stream>>>(out, stats);

    // K4: normalize + relu + residual (in place on out)
    finalize_kernel<<<2048, 256, 0, stream>>>(stats, gamma, beta, node_feats, out);
}

// Round 2
// 780.441 us; speedup vs baseline: 3.7340x; 3.7340x over previous
//
#include <hip/hip_runtime.h>

#define N_NODES 100000
#define N_EDGES 1600000
#define F 128
#define BN_EPS 1e-5f
#define SCAN_T 1024

// Workspace layout (bytes):
//   [0, 1024)                    stats: 256 floats (sum, sumsq)
//   [1024, 401024)               deg:   N_NODES ints
//   [401024, 801040)             offsets: N_NODES+1 ints (padded)
//   [801040, 1201040)            cursor:  N_NODES ints
//   [1201040, 7601040)           csr_src: N_EDGES ints
#define O_STATS   0
#define O_DEG     1024
#define O_OFF     401024
#define O_CURSOR  801040
#define O_CSR     1201040

// ---------------------------------------------------------------------------
// K1: histogram of dst -> deg[]
// ---------------------------------------------------------------------------
__global__ __launch_bounds__(256) void hist_kernel(
    const int* __restrict__ dst, int* __restrict__ deg)
{
    int e = blockIdx.x * blockDim.x + threadIdx.x;
    if (e < N_EDGES) atomicAdd(&deg[dst[e]], 1);
}

// ---------------------------------------------------------------------------
// K2: single-block exclusive scan of deg -> offsets, cursor
// ---------------------------------------------------------------------------
__global__ __launch_bounds__(SCAN_T) void scan_kernel(
    const int* __restrict__ deg,
    int* __restrict__ offsets,
    int* __restrict__ cursor)
{
    const int CH = (N_NODES + SCAN_T - 1) / SCAN_T;   // 98
    const int t = threadIdx.x;
    const int beg = t * CH;
    const int end = min(beg + CH, N_NODES);

    int sum = 0;
    for (int i = beg; i < end; ++i) sum += deg[i];

    __shared__ int ls[SCAN_T];
    ls[t] = sum;
    __syncthreads();
    for (int d = 1; d < SCAN_T; d <<= 1) {
        int v = (t >= d) ? ls[t - d] : 0;
        __syncthreads();
        ls[t] += v;
        __syncthreads();
    }
    int run = ls[t] - sum;   // exclusive base for this chunk
    for (int i = beg; i < end; ++i) {
        offsets[i] = run;
        cursor[i]  = run;
        run += deg[i];
    }
    if (t == SCAN_T - 1) offsets[N_NODES] = N_EDGES;
}

// ---------------------------------------------------------------------------
// K3: bucket fill: csr_src[cursor[dst]++] = src
// ---------------------------------------------------------------------------
__global__ __launch_bounds__(256) void fill_kernel(
    const int* __restrict__ src,
    const int* __restrict__ dst,
    int* __restrict__ cursor,
    int* __restrict__ csr_src)
{
    int e = blockIdx.x * blockDim.x + threadIdx.x;
    if (e >= N_EDGES) return;
    int d = dst[e];
    int pos = atomicAdd(&cursor[d], 1);
    csr_src[pos] = src[e];
}

// ---------------------------------------------------------------------------
// K4: pull-gather: aggx[v] = X[v] + sum_{e in CSR[v]} X[src[e]]
// 32 lanes per node; lane handles one float4 (4 cols).
// ---------------------------------------------------------------------------
__global__ __launch_bounds__(256) void gather_kernel(
    const float* __restrict__ X,
    const int* __restrict__ offsets,
    const int* __restrict__ csr_src,
    float* __restrict__ aggx)
{
    int g    = blockIdx.x * 8 + (threadIdx.x >> 5);   // node id
    int lane = threadIdx.x & 31;
    if (g >= N_NODES) return;

    const float4* X4 = (const float4*)X;
    float4 acc = X4[(size_t)g * 32 + lane];           // self loop

    int beg = offsets[g];
    int end = offsets[g + 1];

    int e = beg;
    // 2-deep unroll for a bit of MLP
    for (; e + 1 < end; e += 2) {
        int s0 = csr_src[e];
        int s1 = csr_src[e + 1];
        float4 v0 = X4[(size_t)s0 * 32 + lane];
        float4 v1 = X4[(size_t)s1 * 32 + lane];
        acc.x += v0.x; acc.y += v0.y; acc.z += v0.z; acc.w += v0.w;
        acc.x += v1.x; acc.y += v1.y; acc.z += v1.z; acc.w += v1.w;
    }
    if (e < end) {
        int s0 = csr_src[e];
        float4 v0 = X4[(size_t)s0 * 32 + lane];
        acc.x += v0.x; acc.y += v0.y; acc.z += v0.z; acc.w += v0.w;
    }
    ((float4*)aggx)[(size_t)g * 32 + lane] = acc;
}

// ---------------------------------------------------------------------------
// K5: out = aggx @ W^T + (deg+1)*b, IN PLACE on aggx (=d_out).
// Row blocks are block-exclusive so in-place is safe.
// ---------------------------------------------------------------------------
__global__ __launch_bounds__(256) void gemm_kernel(
    float* AOut,                      // [N_NODES,128] read as A, written as out
    const float* __restrict__ W,     // [128,128] row-major [out][in]
    const float* __restrict__ bias,  // [128]
    const int* __restrict__ deg)     // [N_NODES]
{
    __shared__ float As[64 * 36];
    __shared__ float Ws[32 * 132];

    const int t   = threadIdx.x;
    const int tc  = t & 31;
    const int tr  = t >> 5;
    const int c0  = tc * 4;
    const int r0  = tr * 8;
    const int row0 = blockIdx.x * 64;

    float acc[8][4];
#pragma unroll
    for (int r = 0; r < 8; r++)
#pragma unroll
        for (int c = 0; c < 4; c++) acc[r][c] = 0.0f;

    for (int kc = 0; kc < 128; kc += 32) {
        __syncthreads();
#pragma unroll
        for (int i = 0; i < 2; i++) {
            int idx = t * 2 + i;
            int r   = idx >> 3;
            int k4  = idx & 7;
            int grow = row0 + r;
            float4 v = make_float4(0.f, 0.f, 0.f, 0.f);
            if (grow < N_NODES)
                v = *(const float4*)&AOut[(size_t)grow * F + kc + k4 * 4];
            *(float4*)&As[r * 36 + k4 * 4] = v;
        }
#pragma unroll
        for (int i = 0; i < 4; i++) {
            int idx = t + i * 256;
            int k4  = idx & 7;
            int c   = idx >> 3;
            float4 v = *(const float4*)&W[(size_t)c * F + kc + k4 * 4];
            Ws[(k4 * 4 + 0) * 132 + c] = v.x;
            Ws[(k4 * 4 + 1) * 132 + c] = v.y;
            Ws[(k4 * 4 + 2) * 132 + c] = v.z;
            Ws[(k4 * 4 + 3) * 132 + c] = v.w;
        }
        __syncthreads();

#pragma unroll
        for (int k4 = 0; k4 < 8; k4++) {
            float4 a4[8];
#pragma unroll
            for (int r = 0; r < 8; r++)
                a4[r] = *(const float4*)&As[(r0 + r) * 36 + k4 * 4];
            float4 w4[4];
#pragma unroll
            for (int j = 0; j < 4; j++)
                w4[j] = *(const float4*)&Ws[(k4 * 4 + j) * 132 + c0];
#pragma unroll
            for (int r = 0; r < 8; r++) {
                float4 a = a4[r];
                acc[r][0] += a.x * w4[0].x + a.y * w4[1].x + a.z * w4[2].x + a.w * w4[3].x;
                acc[r][1] += a.x * w4[0].y + a.y * w4[1].y + a.z * w4[2].y + a.w * w4[3].y;
                acc[r][2] += a.x * w4[0].z + a.y * w4[1].z + a.z * w4[2].z + a.w * w4[3].z;
                acc[r][3] += a.x * w4[0].w + a.y * w4[1].w + a.z * w4[2].w + a.w * w4[3].w;
            }
        }
    }
    __syncthreads();   // all reads of this block's A rows done before in-place write

    float4 bv = *(const float4*)&bias[c0];
#pragma unroll
    for (int r = 0; r < 8; r++) {
        int grow = row0 + r0 + r;
        if (grow < N_NODES) {
            float scale = (float)(deg[grow] + 1);
            float4 o;
            o.x = acc[r][0] + scale * bv.x;
            o.y = acc[r][1] + scale * bv.y;
            o.z = acc[r][2] + scale * bv.z;
            o.w = acc[r][3] + scale * bv.w;
            *(float4*)&AOut[(size_t)grow * F + c0] = o;
        }
    }
}

// ---------------------------------------------------------------------------
// K6: per-feature sum and sumsq. stats[0:128]=sum, [128:256]=sumsq
// ---------------------------------------------------------------------------
__global__ __launch_bounds__(256) void stats_kernel(
    const float* __restrict__ agg,
    float* __restrict__ stats)
{
    const int t    = threadIdx.x;
    const int tc   = t & 31;
    const int trow = t >> 5;
    const int c0   = tc * 4;

    float4 sum = make_float4(0.f, 0.f, 0.f, 0.f);
    float4 ss  = make_float4(0.f, 0.f, 0.f, 0.f);
    for (int r = blockIdx.x * 8 + trow; r < N_NODES; r += gridDim.x * 8) {
        float4 v = *(const float4*)&agg[(size_t)r * F + c0];
        sum.x += v.x; sum.y += v.y; sum.z += v.z; sum.w += v.w;
        ss.x  += v.x * v.x; ss.y += v.y * v.y; ss.z += v.z * v.z; ss.w += v.w * v.w;
    }

    __shared__ float red[256 * 8];
    float* my = &red[t * 8];
    my[0] = sum.x; my[1] = sum.y; my[2] = sum.z; my[3] = sum.w;
    my[4] = ss.x;  my[5] = ss.y;  my[6] = ss.z;  my[7] = ss.w;
    __syncthreads();

    if (t < 32) {
        float a8[8];
#pragma unroll
        for (int j = 0; j < 8; j++) a8[j] = red[t * 8 + j];
        for (int g = 1; g < 8; g++)
#pragma unroll
            for (int j = 0; j < 8; j++) a8[j] += red[(g * 32 + t) * 8 + j];
#pragma unroll
        for (int j = 0; j < 4; j++) {
            unsafeAtomicAdd(&stats[c0 + j],       a8[j]);
            unsafeAtomicAdd(&stats[128 + c0 + j], a8[4 + j]);
        }
    }
}

// ---------------------------------------------------------------------------
// K7: out = relu(gamma*(agg-mean)*rsqrt(var+eps)+beta) + node_feats (in place)
// ---------------------------------------------------------------------------
__global__ __launch_bounds__(256) void finalize_kernel(
    const float* __restrict__ stats,
    const float* __restrict__ gamma,
    const float* __restrict__ beta,
    const float* __restrict__ x,
    float* __restrict__ agg)
{
    __shared__ float s_scale[128];
    __shared__ float s_shift[128];
    const int t = threadIdx.x;
    if (t < 128) {
        const float inv_n = 1.0f / (float)N_NODES;
        float mean = stats[t] * inv_n;
        float var  = stats[128 + t] * inv_n - mean * mean;
        float sc   = gamma[t] * rsqrtf(var + BN_EPS);
        s_scale[t] = sc;
        s_shift[t] = beta[t] - mean * sc;
    }
    __syncthreads();

    const long long total = (long long)N_NODES * F / 4;
    long long i0 = (long long)blockIdx.x * blockDim.x + t;
    for (long long i = i0; i < total; i += (long long)gridDim.x * blockDim.x) {
        int cb = (int)(i & 31) * 4;
        float4 v  = ((const float4*)agg)[i];
        float4 xf = ((const float4*)x)[i];
        float4 o;
        o.x = fmaxf(v.x * s_scale[cb + 0] + s_shift[cb + 0], 0.f) + xf.x;
        o.y = fmaxf(v.y * s_scale[cb + 1] + s_shift[cb + 1], 0.f) + xf.y;
        o.z = fmaxf(v.z * s_scale[cb + 2] + s_shift[cb + 2], 0.f) + xf.z;
        o.w = fmaxf(v.w * s_scale[cb + 3] + s_shift[cb + 3], 0.f) + xf.w;
        ((float4*)agg)[i] = o;
    }
}

// ---------------------------------------------------------------------------
extern "C" void kernel_launch(void* const* d_in, const int* in_sizes, int n_in,
                              void* d_out, int out_size, void* d_ws, size_t ws_size,
                              hipStream_t stream) {
    const float* node_feats = (const float*)d_in[0];
    const float* W          = (const float*)d_in[1];
    const float* b          = (const float*)d_in[2];
    const float* gamma      = (const float*)d_in[3];
    const float* beta       = (const float*)d_in[4];
    const int*   src        = (const int*)d_in[5];
    const int*   dst        = (const int*)d_in[6];

    float* out     = (float*)d_out;
    char*  ws      = (char*)d_ws;
    float* stats   = (float*)(ws + O_STATS);
    int*   deg     = (int*)(ws + O_DEG);
    int*   offsets = (int*)(ws + O_OFF);
    int*   cursor  = (int*)(ws + O_CURSOR);
    int*   csr_src = (int*)(ws + O_CSR);

    // zero stats + deg
    hipMemsetAsync(d_ws, 0, O_OFF, stream);

    hist_kernel<<<N_EDGES / 256, 256, 0, stream>>>(dst, deg);
    scan_kernel<<<1, SCAN_T, 0, stream>>>(deg, offsets, cursor);
    fill_kernel<<<N_EDGES / 256, 256, 0, stream>>>(src, dst, cursor, csr_src);

    // aggregate raw features into d_out
    gather_kernel<<<(N_NODES + 7) / 8, 256, 0, stream>>>(node_feats, offsets, csr_src, out);

    // project in place, bias scaled by (deg+1)
    gemm_kernel<<<(N_NODES + 63) / 64, 256, 0, stream>>>(out, W, b, deg);

    stats_kernel<<<1024, 256, 0, stream>>>(out, stats);
    finalize_kernel<<<2048, 256, 0, stream>>>(stats, gamma, beta, node_feats, out);
}

// Round 3
// 562.812 us; speedup vs baseline: 5.1779x; 1.3867x over previous
//
#include <hip/hip_runtime.h>

#define N_NODES 100000
#define N_EDGES 1600000
#define F 128
#define BN_EPS 1e-5f
#define SB 512                                   // deg elements per scan block
#define SCAN_BLOCKS ((N_NODES + SB - 1) / SB)    // 196

// Workspace layout (bytes):
//   [0, 1024)            stats: 256 floats (sum, sumsq)
//   [1024, 401024)       deg:     N_NODES ints
//   [401024, 801040)     offsets: N_NODES+1 ints (padded)
//   [801040, 1201040)    cursor:  N_NODES ints
//   [1201040, 7601040)   csr_src: N_EDGES ints
//   [7601040, 7602064)   bsum:    256 ints
#define O_STATS   0
#define O_DEG     1024
#define O_OFF     401024
#define O_CURSOR  801040
#define O_CSR     1201040
#define O_BSUM    7601040

// ---------------------------------------------------------------------------
// K1: histogram of dst -> deg[]
// ---------------------------------------------------------------------------
__global__ __launch_bounds__(256) void hist_kernel(
    const int* __restrict__ dst, int* __restrict__ deg)
{
    int e = blockIdx.x * blockDim.x + threadIdx.x;
    if (e < N_EDGES) atomicAdd(&deg[dst[e]], 1);
}

// ---------------------------------------------------------------------------
// K2a: per-block partial sums of deg (512 elems / block)
// ---------------------------------------------------------------------------
__global__ __launch_bounds__(256) void scan_partial(
    const int* __restrict__ deg, int* __restrict__ bsum)
{
    const int t = threadIdx.x;
    const int i0 = blockIdx.x * SB + t * 2;
    int v0 = (i0 < N_NODES)     ? deg[i0]     : 0;
    int v1 = (i0 + 1 < N_NODES) ? deg[i0 + 1] : 0;
    __shared__ int red[256];
    red[t] = v0 + v1;
    __syncthreads();
    for (int d = 128; d > 0; d >>= 1) {
        if (t < d) red[t] += red[t + d];
        __syncthreads();
    }
    if (t == 0) bsum[blockIdx.x] = red[0];
}

// ---------------------------------------------------------------------------
// K2b: single tiny block: exclusive scan of the block sums (in place)
// ---------------------------------------------------------------------------
__global__ __launch_bounds__(256) void scan_bsum(int* __restrict__ bsum)
{
    const int t = threadIdx.x;
    __shared__ int ls[256];
    int v = (t < SCAN_BLOCKS) ? bsum[t] : 0;
    ls[t] = v;
    __syncthreads();
    for (int d = 1; d < 256; d <<= 1) {
        int u = (t >= d) ? ls[t - d] : 0;
        __syncthreads();
        ls[t] += u;
        __syncthreads();
    }
    if (t < SCAN_BLOCKS) bsum[t] = ls[t] - v;    // exclusive base
}

// ---------------------------------------------------------------------------
// K2c: intra-block exclusive scan + base -> offsets, cursor
// ---------------------------------------------------------------------------
__global__ __launch_bounds__(256) void scan_final(
    const int* __restrict__ deg,
    const int* __restrict__ bsum,
    int* __restrict__ offsets,
    int* __restrict__ cursor)
{
    const int t = threadIdx.x;
    const int i0 = blockIdx.x * SB + t * 2;
    int v0 = (i0 < N_NODES)     ? deg[i0]     : 0;
    int v1 = (i0 + 1 < N_NODES) ? deg[i0 + 1] : 0;
    int s = v0 + v1;
    __shared__ int ls[256];
    ls[t] = s;
    __syncthreads();
    for (int d = 1; d < 256; d <<= 1) {
        int u = (t >= d) ? ls[t - d] : 0;
        __syncthreads();
        ls[t] += u;
        __syncthreads();
    }
    int ex = bsum[blockIdx.x] + ls[t] - s;
    if (i0 < N_NODES)     { offsets[i0]     = ex;      cursor[i0]     = ex; }
    if (i0 + 1 < N_NODES) { offsets[i0 + 1] = ex + v0; cursor[i0 + 1] = ex + v0; }
    if (blockIdx.x == gridDim.x - 1 && t == 255) offsets[N_NODES] = N_EDGES;
}

// ---------------------------------------------------------------------------
// K3: bucket fill: csr_src[cursor[dst]++] = src
// ---------------------------------------------------------------------------
__global__ __launch_bounds__(256) void fill_kernel(
    const int* __restrict__ src,
    const int* __restrict__ dst,
    int* __restrict__ cursor,
    int* __restrict__ csr_src)
{
    int e = blockIdx.x * blockDim.x + threadIdx.x;
    if (e >= N_EDGES) return;
    int d = dst[e];
    int pos = atomicAdd(&cursor[d], 1);
    csr_src[pos] = src[e];
}

// ---------------------------------------------------------------------------
// K4: pull-gather: aggx[v] = X[v] + sum_{e in CSR[v]} X[src[e]]
// 32 lanes per node; lane handles one float4 (4 cols).
// ---------------------------------------------------------------------------
__global__ __launch_bounds__(256) void gather_kernel(
    const float* __restrict__ X,
    const int* __restrict__ offsets,
    const int* __restrict__ csr_src,
    float* __restrict__ aggx)
{
    int g    = blockIdx.x * 8 + (threadIdx.x >> 5);   // node id
    int lane = threadIdx.x & 31;
    if (g >= N_NODES) return;

    const float4* X4 = (const float4*)X;
    float4 acc = X4[(size_t)g * 32 + lane];           // self loop

    int beg = offsets[g];
    int end = offsets[g + 1];

    int e = beg;
    for (; e + 3 < end; e += 4) {
        int s0 = csr_src[e];
        int s1 = csr_src[e + 1];
        int s2 = csr_src[e + 2];
        int s3 = csr_src[e + 3];
        float4 v0 = X4[(size_t)s0 * 32 + lane];
        float4 v1 = X4[(size_t)s1 * 32 + lane];
        float4 v2 = X4[(size_t)s2 * 32 + lane];
        float4 v3 = X4[(size_t)s3 * 32 + lane];
        acc.x += v0.x + v1.x + v2.x + v3.x;
        acc.y += v0.y + v1.y + v2.y + v3.y;
        acc.z += v0.z + v1.z + v2.z + v3.z;
        acc.w += v0.w + v1.w + v2.w + v3.w;
    }
    for (; e < end; ++e) {
        int s0 = csr_src[e];
        float4 v0 = X4[(size_t)s0 * 32 + lane];
        acc.x += v0.x; acc.y += v0.y; acc.z += v0.z; acc.w += v0.w;
    }
    ((float4*)aggx)[(size_t)g * 32 + lane] = acc;
}

// ---------------------------------------------------------------------------
// K5: out = aggx @ W^T + (deg+1)*b, IN PLACE on aggx (=d_out).
// ---------------------------------------------------------------------------
__global__ __launch_bounds__(256) void gemm_kernel(
    float* AOut,                     // [N_NODES,128] read as A, written as out
    const float* __restrict__ W,    // [128,128] row-major [out][in]
    const float* __restrict__ bias, // [128]
    const int* __restrict__ deg)    // [N_NODES]
{
    __shared__ float As[64 * 36];
    __shared__ float Ws[32 * 132];

    const int t   = threadIdx.x;
    const int tc  = t & 31;
    const int tr  = t >> 5;
    const int c0  = tc * 4;
    const int r0  = tr * 8;
    const int row0 = blockIdx.x * 64;

    float acc[8][4];
#pragma unroll
    for (int r = 0; r < 8; r++)
#pragma unroll
        for (int c = 0; c < 4; c++) acc[r][c] = 0.0f;

    for (int kc = 0; kc < 128; kc += 32) {
        __syncthreads();
#pragma unroll
        for (int i = 0; i < 2; i++) {
            int idx = t * 2 + i;
            int r   = idx >> 3;
            int k4  = idx & 7;
            int grow = row0 + r;
            float4 v = make_float4(0.f, 0.f, 0.f, 0.f);
            if (grow < N_NODES)
                v = *(const float4*)&AOut[(size_t)grow * F + kc + k4 * 4];
            *(float4*)&As[r * 36 + k4 * 4] = v;
        }
#pragma unroll
        for (int i = 0; i < 4; i++) {
            int idx = t + i * 256;
            int k4  = idx & 7;
            int c   = idx >> 3;
            float4 v = *(const float4*)&W[(size_t)c * F + kc + k4 * 4];
            Ws[(k4 * 4 + 0) * 132 + c] = v.x;
            Ws[(k4 * 4 + 1) * 132 + c] = v.y;
            Ws[(k4 * 4 + 2) * 132 + c] = v.z;
            Ws[(k4 * 4 + 3) * 132 + c] = v.w;
        }
        __syncthreads();

#pragma unroll
        for (int k4 = 0; k4 < 8; k4++) {
            float4 a4[8];
#pragma unroll
            for (int r = 0; r < 8; r++)
                a4[r] = *(const float4*)&As[(r0 + r) * 36 + k4 * 4];
            float4 w4[4];
#pragma unroll
            for (int j = 0; j < 4; j++)
                w4[j] = *(const float4*)&Ws[(k4 * 4 + j) * 132 + c0];
#pragma unroll
            for (int r = 0; r < 8; r++) {
                float4 a = a4[r];
                acc[r][0] += a.x * w4[0].x + a.y * w4[1].x + a.z * w4[2].x + a.w * w4[3].x;
                acc[r][1] += a.x * w4[0].y + a.y * w4[1].y + a.z * w4[2].y + a.w * w4[3].y;
                acc[r][2] += a.x * w4[0].z + a.y * w4[1].z + a.z * w4[2].z + a.w * w4[3].z;
                acc[r][3] += a.x * w4[0].w + a.y * w4[1].w + a.z * w4[2].w + a.w * w4[3].w;
            }
        }
    }
    __syncthreads();   // all reads of this block's A rows done before in-place write

    float4 bv = *(const float4*)&bias[c0];
#pragma unroll
    for (int r = 0; r < 8; r++) {
        int grow = row0 + r0 + r;
        if (grow < N_NODES) {
            float scale = (float)(deg[grow] + 1);
            float4 o;
            o.x = acc[r][0] + scale * bv.x;
            o.y = acc[r][1] + scale * bv.y;
            o.z = acc[r][2] + scale * bv.z;
            o.w = acc[r][3] + scale * bv.w;
            *(float4*)&AOut[(size_t)grow * F + c0] = o;
        }
    }
}

// ---------------------------------------------------------------------------
// K6: per-feature sum and sumsq. stats[0:128]=sum, [128:256]=sumsq
// ---------------------------------------------------------------------------
__global__ __launch_bounds__(256) void stats_kernel(
    const float* __restrict__ agg,
    float* __restrict__ stats)
{
    const int t    = threadIdx.x;
    const int tc   = t & 31;
    const int trow = t >> 5;
    const int c0   = tc * 4;

    float4 sum = make_float4(0.f, 0.f, 0.f, 0.f);
    float4 ss  = make_float4(0.f, 0.f, 0.f, 0.f);
    for (int r = blockIdx.x * 8 + trow; r < N_NODES; r += gridDim.x * 8) {
        float4 v = *(const float4*)&agg[(size_t)r * F + c0];
        sum.x += v.x; sum.y += v.y; sum.z += v.z; sum.w += v.w;
        ss.x  += v.x * v.x; ss.y += v.y * v.y; ss.z += v.z * v.z; ss.w += v.w * v.w;
    }

    __shared__ float red[256 * 8];
    float* my = &red[t * 8];
    my[0] = sum.x; my[1] = sum.y; my[2] = sum.z; my[3] = sum.w;
    my[4] = ss.x;  my[5] = ss.y;  my[6] = ss.z;  my[7] = ss.w;
    __syncthreads();

    if (t < 32) {
        float a8[8];
#pragma unroll
        for (int j = 0; j < 8; j++) a8[j] = red[t * 8 + j];
        for (int g = 1; g < 8; g++)
#pragma unroll
            for (int j = 0; j < 8; j++) a8[j] += red[(g * 32 + t) * 8 + j];
#pragma unroll
        for (int j = 0; j < 4; j++) {
            unsafeAtomicAdd(&stats[c0 + j],       a8[j]);
            unsafeAtomicAdd(&stats[128 + c0 + j], a8[4 + j]);
        }
    }
}

// ---------------------------------------------------------------------------
// K7: out = relu(gamma*(agg-mean)*rsqrt(var+eps)+beta) + node_feats (in place)
// ---------------------------------------------------------------------------
__global__ __launch_bounds__(256) void finalize_kernel(
    const float* __restrict__ stats,
    const float* __restrict__ gamma,
    const float* __restrict__ beta,
    const float* __restrict__ x,
    float* __restrict__ agg)
{
    __shared__ float s_scale[128];
    __shared__ float s_shift[128];
    const int t = threadIdx.x;
    if (t < 128) {
        const float inv_n = 1.0f / (float)N_NODES;
        float mean = stats[t] * inv_n;
        float var  = stats[128 + t] * inv_n - mean * mean;
        float sc   = gamma[t] * rsqrtf(var + BN_EPS);
        s_scale[t] = sc;
        s_shift[t] = beta[t] - mean * sc;
    }
    __syncthreads();

    const long long total = (long long)N_NODES * F / 4;
    long long i0 = (long long)blockIdx.x * blockDim.x + t;
    for (long long i = i0; i < total; i += (long long)gridDim.x * blockDim.x) {
        int cb = (int)(i & 31) * 4;
        float4 v  = ((const float4*)agg)[i];
        float4 xf = ((const float4*)x)[i];
        float4 o;
        o.x = fmaxf(v.x * s_scale[cb + 0] + s_shift[cb + 0], 0.f) + xf.x;
        o.y = fmaxf(v.y * s_scale[cb + 1] + s_shift[cb + 1], 0.f) + xf.y;
        o.z = fmaxf(v.z * s_scale[cb + 2] + s_shift[cb + 2], 0.f) + xf.z;
        o.w = fmaxf(v.w * s_scale[cb + 3] + s_shift[cb + 3], 0.f) + xf.w;
        ((float4*)agg)[i] = o;
    }
}

// ---------------------------------------------------------------------------
extern "C" void kernel_launch(void* const* d_in, const int* in_sizes, int n_in,
                              void* d_out, int out_size, void* d_ws, size_t ws_size,
                              hipStream_t stream) {
    const float* node_feats = (const float*)d_in[0];
    const float* W          = (const float*)d_in[1];
    const float* b          = (const float*)d_in[2];
    const float* gamma      = (const float*)d_in[3];
    const float* beta       = (const float*)d_in[4];
    const int*   src        = (const int*)d_in[5];
    const int*   dst        = (const int*)d_in[6];

    float* out     = (float*)d_out;
    char*  ws      = (char*)d_ws;
    float* stats   = (float*)(ws + O_STATS);
    int*   deg     = (int*)(ws + O_DEG);
    int*   offsets = (int*)(ws + O_OFF);
    int*   cursor  = (int*)(ws + O_CURSOR);
    int*   csr_src = (int*)(ws + O_CSR);
    int*   bsum    = (int*)(ws + O_BSUM);

    // zero stats + deg
    hipMemsetAsync(d_ws, 0, O_OFF, stream);

    hist_kernel<<<N_EDGES / 256, 256, 0, stream>>>(dst, deg);

    scan_partial<<<SCAN_BLOCKS, 256, 0, stream>>>(deg, bsum);
    scan_bsum<<<1, 256, 0, stream>>>(bsum);
    scan_final<<<SCAN_BLOCKS, 256, 0, stream>>>(deg, bsum, offsets, cursor);

    fill_kernel<<<N_EDGES / 256, 256, 0, stream>>>(src, dst, cursor, csr_src);

    // aggregate raw features into d_out
    gather_kernel<<<(N_NODES + 7) / 8, 256, 0, stream>>>(node_feats, offsets, csr_src, out);

    // project in place, bias scaled by (deg+1)
    gemm_kernel<<<(N_NODES + 63) / 64, 256, 0, stream>>>(out, W, b, deg);

    stats_kernel<<<1024, 256, 0, stream>>>(out, stats);
    finalize_kernel<<<2048, 256, 0, stream>>>(stats, gamma, beta, node_feats, out);
}